// Round 9
// baseline (207.930 us; speedup 1.0000x reference)
//
#include <hip/hip_runtime.h>
#include <math.h>

#define SL 2048   // sequence length L
#define NB 32     // batch
#define NH 128    // feature dim H
#define NP 256    // state dim P (complex)
#define NP2 512   // interleaved real/imag columns

typedef short bf16x8 __attribute__((ext_vector_type(8)));
typedef float f32x4  __attribute__((ext_vector_type(4)));

static __device__ __forceinline__ unsigned short f2bf(float x) {
    unsigned u = __float_as_uint(x);
    return (unsigned short)((u + 0x7fffu + ((u >> 16) & 1u)) >> 16);  // RNE
}
static __device__ __forceinline__ float bf2f(unsigned short h) {
    return __uint_as_float(((unsigned)h) << 16);
}
static __device__ __forceinline__ void discretize(
    const float* __restrict__ logLr, const float* __restrict__ Lim,
    const float* __restrict__ logDt, int p, float& wr, float& wi)
{
    const float Lr = expf(logLr[p]);
    const float dt = expf(logDt[p]);
    const float ew = expf(-Lr * dt);
    const float ang = Lim[p] * dt;
    wr = ew * cosf(ang); wi = ew * sinf(ang);
}

// Load one MFMA B-fragment (8 bf16 = row l, h-slice [h0,h0+8)) straight from
// global u with in-register RNE conversion. Bitwise-identical to the old
// LDS-staged path (same floats, same f2bf) -> gA/gF carry consistency holds.
static __device__ __forceinline__ bf16x8 load_u_frag(
    const float* __restrict__ u, int l, int b, int h0)
{
    const float* up = u + (size_t)l * (NB * NH) + b * NH + h0;
    const float4 a = *(const float4*)(up + 0);
    const float4 d = *(const float4*)(up + 4);
    uint4 r;
    r.x = (unsigned)f2bf(a.x) | ((unsigned)f2bf(a.y) << 16);
    r.y = (unsigned)f2bf(a.z) | ((unsigned)f2bf(a.w) << 16);
    r.z = (unsigned)f2bf(d.x) | ((unsigned)f2bf(d.y) << 16);
    r.w = (unsigned)f2bf(d.z) | ((unsigned)f2bf(d.w) << 16);
    union { uint4 u4; bf16x8 v; } cv; cv.u4 = r;
    return cv.v;
}

// ---------------------------------------------------------------------------
// k0: pack BhatF, fragment-major f_p*B_tilde: BhatF[(h>>5)<<14 | p'<<5 | h&31]
// (coalesced 1 KB af loads) and ChatF[kk<<12 | h<<5 | col&31] (gF's GEMM2 af).
// ---------------------------------------------------------------------------
__global__ __launch_bounds__(256) void k0(
    const float* __restrict__ logLr, const float* __restrict__ Lim,
    const float* __restrict__ logDt,
    const float* __restrict__ Br, const float* __restrict__ Bi,
    const float* __restrict__ Cr, const float* __restrict__ Ci,
    unsigned short* __restrict__ BhatF, unsigned short* __restrict__ ChatF)
{
    const int tid = blockIdx.x * 256 + threadIdx.x;  // 32768 = P*H
    const int p = tid >> 7, h = tid & 127;
    float wr, wi; discretize(logLr, Lim, logDt, p, wr, wi);
    const float Lr = expf(logLr[p]), li = Lim[p];
    const float nr = wr - 1.0f, ni = wi;
    const float den = Lr * Lr + li * li;
    const float fr = (-nr * Lr + ni * li) / den;
    const float fi = (-ni * Lr - nr * li) / den;
    const float br = Br[p * NH + h], bi = Bi[p * NH + h];
    BhatF[((size_t)(h >> 5) << 14) + ((2 * p)     << 5) + (h & 31)] = f2bf(fr * br - fi * bi);
    BhatF[((size_t)(h >> 5) << 14) + ((2 * p + 1) << 5) + (h & 31)] = f2bf(fr * bi + fi * br);
    const int col0 = 2 * p, col1 = 2 * p + 1;
    ChatF[((size_t)(col0 >> 5) << 12) + (h << 5) + (col0 & 31)] = f2bf(Cr[h * NP + p]);
    ChatF[((size_t)(col1 >> 5) << 12) + (h << 5) + (col1 & 31)] = f2bf(-Ci[h * NP + p]);
}

// ---------------------------------------------------------------------------
// gA (carry-only): ONE independent 32-l x 256-p' tile per block (64 x 2 x 32).
// NEW: no us LDS stage — bfr fragments loaded directly from global u (L3-hot)
// with in-register f2bf. LDS = xs only (16512 B) -> 8 blocks/CU (wave cap);
// single barrier. (256,4): the only proven-spill-free bound (r4/r5 lesson).
// ---------------------------------------------------------------------------
__global__ __launch_bounds__(256, 4) void gA(
    const float* __restrict__ u, const unsigned short* __restrict__ BhatF,
    const float* __restrict__ logLr, const float* __restrict__ Lim,
    const float* __restrict__ logDt, float2* __restrict__ part)
{
    __shared__ unsigned xs[32 * 129];        // out tile [l][128 complex], pitch 129

    const int m  = blockIdx.x;               // 32-l chunk, 0..63
    const int ph = blockIdx.y;               // p-half, 0..1
    const int b  = blockIdx.z;
    const int tid = threadIdx.x;
    const int w = tid >> 6, lane = tid & 63;
    const int q = lane >> 4, c = lane & 15;
    const int pbase = ph * 256 + w * 64;     // wave's 64 p' (global)
    const int l0 = m * 32;

    f32x4 acc[4][2];
    #pragma unroll
    for (int mt = 0; mt < 4; ++mt)
        #pragma unroll
        for (int nt = 0; nt < 2; ++nt) acc[mt][nt] = (f32x4){0.f, 0.f, 0.f, 0.f};

    #pragma unroll
    for (int kk = 0; kk < 4; ++kk) {
        bf16x8 af[4];
        #pragma unroll
        for (int mt = 0; mt < 4; ++mt)
            af[mt] = *(const bf16x8*)(BhatF + ((size_t)kk << 14)
                                      + ((pbase + 16 * mt + c) << 5) + 8 * q);
        bf16x8 bfr[2];
        #pragma unroll
        for (int nt = 0; nt < 2; ++nt)
            bfr[nt] = load_u_frag(u, l0 + 16 * nt + c, b, kk * 32 + 8 * q);
        #pragma unroll
        for (int mt = 0; mt < 4; ++mt)
            #pragma unroll
            for (int nt = 0; nt < 2; ++nt)
                acc[mt][nt] = __builtin_amdgcn_mfma_f32_16x16x32_bf16(
                    af[mt], bfr[nt], acc[mt][nt], 0, 0, 0);
    }

    // stash xs (bf16 pack — identical rounding to the old bu store)
    #pragma unroll
    for (int mt = 0; mt < 4; ++mt)
        #pragma unroll
        for (int nt = 0; nt < 2; ++nt) {
            const int rw  = 16 * nt + c;              // local l row
            const int ppl = w * 64 + 16 * mt + 4 * q; // local p' (0..255)
            ushort4 st;
            st.x = f2bf(acc[mt][nt][0]); st.y = f2bf(acc[mt][nt][1]);
            st.z = f2bf(acc[mt][nt][2]); st.w = f2bf(acc[mt][nt][3]);
            const int col = (ppl >> 1);               // local complex index 0..127
            xs[rw * 129 + col]     = (unsigned)st.x | ((unsigned)st.y << 16);
            xs[rw * 129 + col + 1] = (unsigned)st.z | ((unsigned)st.w << 16);
        }
    __syncthreads();   // xs ready

    // carry-only scan over 32 rows; threads 0..127 own this half's complex cols
    if (tid < 128) {
        float wr, wi; discretize(logLr, Lim, logDt, ph * 128 + tid, wr, wi);
        float sr = 0.f, si = 0.f;
        unsigned va[8], vb[8];
        #pragma unroll
        for (int j = 0; j < 8; ++j) va[j] = xs[j * 129 + tid];
        #pragma unroll
        for (int k8 = 0; k8 < 4; ++k8) {
            if (k8 < 3) {
                #pragma unroll
                for (int j = 0; j < 8; ++j) vb[j] = xs[((k8 + 1) * 8 + j) * 129 + tid];
            }
            #pragma unroll
            for (int j = 0; j < 8; ++j) {
                const float xr = bf2f((unsigned short)(va[j] & 0xffffu));
                const float xi = bf2f((unsigned short)(va[j] >> 16));
                const float tr = wr * sr - wi * si + xr;
                const float ti = wr * si + wi * sr + xi;
                sr = tr; si = ti;
            }
            #pragma unroll
            for (int j = 0; j < 8; ++j) va[j] = vb[j];
        }
        part[((size_t)b * 64 + m) * NP + ph * 128 + tid] = make_float2(sr, si);
    }
}

// ---------------------------------------------------------------------------
// s2: in-place scan of 32-l tile carries -> state ENTERING each tile,
// composed with W32 = w^32, 8-deep prefetch (r6-proven).
// ---------------------------------------------------------------------------
__global__ __launch_bounds__(256) void s2(
    float2* __restrict__ part, const float* __restrict__ logLr,
    const float* __restrict__ Lim, const float* __restrict__ logDt)
{
    const int b = blockIdx.x, p = threadIdx.x;
    float wr, wi; discretize(logLr, Lim, logDt, p, wr, wi);
    float Wr = wr, Wi = wi;
    #pragma unroll
    for (int t = 0; t < 5; ++t) { const float r = Wr * Wr - Wi * Wi; Wi = 2.f * Wr * Wi; Wr = r; }  // w^32
    const size_t base = (size_t)b * 64 * NP + p;
    float sr = 0.f, si = 0.f;
    float2 va[8], vb[8];
    #pragma unroll
    for (int j = 0; j < 8; ++j) va[j] = part[base + (size_t)j * NP];
    #pragma unroll
    for (int k8 = 0; k8 < 8; ++k8) {
        if (k8 < 7) {
            #pragma unroll
            for (int j = 0; j < 8; ++j)
                vb[j] = part[base + (size_t)((k8 + 1) * 8 + j) * NP];
        }
        #pragma unroll
        for (int j = 0; j < 8; ++j) {
            part[base + (size_t)(k8 * 8 + j) * NP] = make_float2(sr, si);  // entry
            const float tr = Wr * sr - Wi * si + va[j].x;
            const float ti = Wr * si + Wi * sr + va[j].y;
            sr = tr; si = ti;
        }
        #pragma unroll
        for (int j = 0; j < 8; ++j) va[j] = vb[j];
    }
}

// ---------------------------------------------------------------------------
// gF: fused GEMM1-recompute + replay + GEMM2 per (b, 32-l chunk).
// NEW: no us LDS stage — bfr direct from global u (identical f2bf path ->
// bitwise-identical Bu as gA). LDS = osb only (16384 B) -> 8 blocks/CU,
// grid 2048 = exactly one resident round. 6 barriers (stage barrier gone).
// ---------------------------------------------------------------------------
__global__ __launch_bounds__(256, 4) void gF(
    const float* __restrict__ u, const unsigned short* __restrict__ BhatF,
    const unsigned short* __restrict__ ChatF,
    const float* __restrict__ logLr, const float* __restrict__ Lim,
    const float* __restrict__ logDt, const float2* __restrict__ Ent,
    const float* __restrict__ Dv, float* __restrict__ out)
{
    __shared__ char osb[16384];              // o half-tile [32 l][128 complex], swizzled

    const int m = blockIdx.x, b = blockIdx.y;   // m: 32-l chunk, 0..63
    const int tid = threadIdx.x;
    const int w = tid >> 6, lane = tid & 63;
    const int q = lane >> 4, c = lane & 15;
    const int hbase = w * 32;              // GEMM2: wave owns a 32-h quadrant
    const int l0 = m * 32;

    f32x4 acc2[2][2];
    #pragma unroll
    for (int mt = 0; mt < 2; ++mt)
        #pragma unroll
        for (int nt = 0; nt < 2; ++nt) acc2[mt][nt] = (f32x4){0.f, 0.f, 0.f, 0.f};

    #pragma unroll 1
    for (int half = 0; half < 2; ++half) {
        // ---- GEMM1 recompute for this half (identical fragments to gA) ----
        const int pbase = half * 256 + w * 64;
        f32x4 acc[4][2];
        #pragma unroll
        for (int mt = 0; mt < 4; ++mt)
            #pragma unroll
            for (int nt = 0; nt < 2; ++nt) acc[mt][nt] = (f32x4){0.f, 0.f, 0.f, 0.f};
        #pragma unroll
        for (int kk = 0; kk < 4; ++kk) {
            bf16x8 af[4];
            #pragma unroll
            for (int mt = 0; mt < 4; ++mt)
                af[mt] = *(const bf16x8*)(BhatF + ((size_t)kk << 14)
                                          + ((pbase + 16 * mt + c) << 5) + 8 * q);
            bf16x8 bfr[2];
            #pragma unroll
            for (int nt = 0; nt < 2; ++nt)
                bfr[nt] = load_u_frag(u, l0 + 16 * nt + c, b, kk * 32 + 8 * q);
            #pragma unroll
            for (int mt = 0; mt < 4; ++mt)
                #pragma unroll
                for (int nt = 0; nt < 2; ++nt)
                    acc[mt][nt] = __builtin_amdgcn_mfma_f32_16x16x32_bf16(
                        af[mt], bfr[nt], acc[mt][nt], 0, 0, 0);
        }

        // ---- stash bf16 Bu into swizzled osb ----
        #pragma unroll
        for (int mt = 0; mt < 4; ++mt)
            #pragma unroll
            for (int nt = 0; nt < 2; ++nt) {
                const int row  = 16 * nt + c;
                const int col2 = w * 32 + 8 * mt + 2 * q;   // complex col, even
                ushort4 st;
                st.x = f2bf(acc[mt][nt][0]); st.y = f2bf(acc[mt][nt][1]);
                st.z = f2bf(acc[mt][nt][2]); st.w = f2bf(acc[mt][nt][3]);
                const unsigned byte = (((unsigned)row << 9)
                                       + (((unsigned)col2 << 2)
                                          ^ (((unsigned)(row & 7)) << 4)));
                uint2 st2 = { (unsigned)st.x | ((unsigned)st.y << 16),
                              (unsigned)st.z | ((unsigned)st.w << 16) };
                *(uint2*)(osb + byte) = st2;
            }
        __syncthreads();   // osb Bu ready

        // ---- replay in place from entry (threads 0..127, batch-loaded) ----
        if (tid < 128) {
            const int p = half * 128 + tid;
            float wr, wi; discretize(logLr, Lim, logDt, p, wr, wi);
            const float2 E = Ent[((size_t)(b * 64 + m)) * NP + p];
            float sr = E.x, si = E.y;
            unsigned va[32];
            #pragma unroll
            for (int j = 0; j < 32; ++j) {
                const unsigned byte = (((unsigned)j << 9)
                                       + (((unsigned)tid << 2)
                                          ^ (((unsigned)(j & 7)) << 4)));
                va[j] = *(const unsigned*)(osb + byte);
            }
            #pragma unroll
            for (int j = 0; j < 32; ++j) {
                const float xr = bf2f((unsigned short)(va[j] & 0xffffu));
                const float xi = bf2f((unsigned short)(va[j] >> 16));
                const float tr = wr * sr - wi * si + xr;
                const float ti = wr * si + wi * sr + xi;
                sr = tr; si = ti;
                va[j] = (unsigned)f2bf(tr) | ((unsigned)f2bf(ti) << 16);
            }
            #pragma unroll
            for (int j = 0; j < 32; ++j) {
                const unsigned byte = (((unsigned)j << 9)
                                       + (((unsigned)tid << 2)
                                          ^ (((unsigned)(j & 7)) << 4)));
                *(unsigned*)(osb + byte) = va[j];
            }
        }
        __syncthreads();   // replayed o ready

        // ---- GEMM2 this half's 8 kk (acc2 persists across halves) ----
        #pragma unroll 4
        for (int kl = 0; kl < 8; ++kl) {
            const int kk = half * 8 + kl;
            bf16x8 af2[2];
            #pragma unroll
            for (int mt = 0; mt < 2; ++mt)
                af2[mt] = *(const bf16x8*)(ChatF + ((size_t)kk << 12)
                                           + ((hbase + (mt << 4) + c) << 5) + (q << 3));
            bf16x8 bfr2[2];
            #pragma unroll
            for (int nt = 0; nt < 2; ++nt) {
                const int r = 16 * nt + c;
                const unsigned byte = ((((unsigned)r << 9) + ((unsigned)kl << 6)
                                        + ((unsigned)q << 4))
                                       ^ (((unsigned)(c & 7)) << 4));
                bfr2[nt] = *(const bf16x8*)(osb + byte);
            }
            #pragma unroll
            for (int mt = 0; mt < 2; ++mt)
                #pragma unroll
                for (int nt = 0; nt < 2; ++nt)
                    acc2[mt][nt] = __builtin_amdgcn_mfma_f32_16x16x32_bf16(
                        af2[mt], bfr2[nt], acc2[mt][nt], 0, 0, 0);
        }
        if (half == 0) __syncthreads();     // osb consumed before overwrite
    }

    // ---- epilogue: D-term + out ----
    #pragma unroll
    for (int mt = 0; mt < 2; ++mt) {
        const int h4 = hbase + 16 * mt + 4 * q;
        const float4 dd = *(const float4*)(Dv + h4);
        #pragma unroll
        for (int nt = 0; nt < 2; ++nt) {
            const int l = l0 + 16 * nt + c;
            const size_t off = ((size_t)l * NB + b) * NH + h4;
            const float4 uu = *(const float4*)(u + off);
            float4 ov;
            ov.x = acc2[mt][nt][0] + dd.x * uu.x;
            ov.y = acc2[mt][nt][1] + dd.y * uu.y;
            ov.z = acc2[mt][nt][2] + dd.z * uu.z;
            ov.w = acc2[mt][nt][3] + dd.w * uu.w;
            *(float4*)(out + off) = ov;
        }
    }
}

extern "C" void kernel_launch(void* const* d_in, const int* in_sizes, int n_in,
                              void* d_out, int out_size, void* d_ws, size_t ws_size,
                              hipStream_t stream)
{
    const float* u     = (const float*)d_in[0];
    const float* logLr = (const float*)d_in[1];
    const float* Lim   = (const float*)d_in[2];
    const float* Btr   = (const float*)d_in[3];
    const float* Bti   = (const float*)d_in[4];
    const float* Ctr   = (const float*)d_in[5];
    const float* Cti   = (const float*)d_in[6];
    const float* Dv    = (const float*)d_in[7];
    const float* logDt = (const float*)d_in[8];
    float* out = (float*)d_out;

    char* ws = (char*)d_ws;
    float2*         part = (float2*)ws;                          //  4,194,304 B (carries -> entries in place)
    unsigned short* Bhat = (unsigned short*)(ws + 4194304);      //    131,072 B (BhatF)
    unsigned short* Chat = (unsigned short*)(ws + 4325376);      //    131,072 B (ChatF)

    k0<<<dim3((NP * NH) / 256), 256, 0, stream>>>(logLr, Lim, logDt,
                                                  Btr, Bti, Ctr, Cti, Bhat, Chat);
    gA<<<dim3(SL / 32, 2, NB), 256, 0, stream>>>(u, Bhat, logLr, Lim, logDt, part);
    s2<<<dim3(NB), 256, 0, stream>>>(part, logLr, Lim, logDt);
    gF<<<dim3(SL / 32, NB), 256, 0, stream>>>(u, Bhat, Chat, logLr, Lim, logDt,
                                              part, Dv, out);
}

// Round 10
// 174.979 us; speedup vs baseline: 1.1883x; 1.1883x over previous
//
#include <hip/hip_runtime.h>
#include <math.h>

#define SL 2048   // sequence length L
#define NB 32     // batch
#define NH 128    // feature dim H
#define NP 256    // state dim P (complex)
#define NP2 512   // interleaved real/imag columns

typedef short bf16x8 __attribute__((ext_vector_type(8)));
typedef float f32x4  __attribute__((ext_vector_type(4)));

static __device__ __forceinline__ unsigned short f2bf(float x) {
    unsigned u = __float_as_uint(x);
    return (unsigned short)((u + 0x7fffu + ((u >> 16) & 1u)) >> 16);  // RNE
}
static __device__ __forceinline__ float bf2f(unsigned short h) {
    return __uint_as_float(((unsigned)h) << 16);
}
static __device__ __forceinline__ void discretize(
    const float* __restrict__ logLr, const float* __restrict__ Lim,
    const float* __restrict__ logDt, int p, float& wr, float& wi)
{
    const float Lr = expf(logLr[p]);
    const float dt = expf(logDt[p]);
    const float ew = expf(-Lr * dt);
    const float ang = Lim[p] * dt;
    wr = ew * cosf(ang); wi = ew * sinf(ang);
}

// ---------------------------------------------------------------------------
// k0: pack BhatF, fragment-major f_p*B_tilde: BhatF[(h>>5)<<14 | p'<<5 | h&31]
// (coalesced 1 KB af loads) and ChatF[kk<<12 | h<<5 | col&31] (gF's GEMM2 af).
// ---------------------------------------------------------------------------
__global__ __launch_bounds__(256) void k0(
    const float* __restrict__ logLr, const float* __restrict__ Lim,
    const float* __restrict__ logDt,
    const float* __restrict__ Br, const float* __restrict__ Bi,
    const float* __restrict__ Cr, const float* __restrict__ Ci,
    unsigned short* __restrict__ BhatF, unsigned short* __restrict__ ChatF)
{
    const int tid = blockIdx.x * 256 + threadIdx.x;  // 32768 = P*H
    const int p = tid >> 7, h = tid & 127;
    float wr, wi; discretize(logLr, Lim, logDt, p, wr, wi);
    const float Lr = expf(logLr[p]), li = Lim[p];
    const float nr = wr - 1.0f, ni = wi;
    const float den = Lr * Lr + li * li;
    const float fr = (-nr * Lr + ni * li) / den;
    const float fi = (-ni * Lr - nr * li) / den;
    const float br = Br[p * NH + h], bi = Bi[p * NH + h];
    BhatF[((size_t)(h >> 5) << 14) + ((2 * p)     << 5) + (h & 31)] = f2bf(fr * br - fi * bi);
    BhatF[((size_t)(h >> 5) << 14) + ((2 * p + 1) << 5) + (h & 31)] = f2bf(fr * bi + fi * br);
    const int col0 = 2 * p, col1 = 2 * p + 1;
    ChatF[((size_t)(col0 >> 5) << 12) + (h << 5) + (col0 & 31)] = f2bf(Cr[h * NP + p]);
    ChatF[((size_t)(col1 >> 5) << 12) + (h << 5) + (col1 & 31)] = f2bf(-Ci[h * NP + p]);
}

// ---------------------------------------------------------------------------
// gA (carry-only): ONE independent 32-l x 256-p' tile per block (64 x 2 x 32).
// r8-exact (LDS us staging restored — r9's direct-global fragment loads were
// a 16KB-strided scatter + spill: FETCH +14 MB, WRITE +24 MB, dur +16 us).
// ---------------------------------------------------------------------------
__global__ __launch_bounds__(256, 4) void gA(
    const float* __restrict__ u, const unsigned short* __restrict__ BhatF,
    const float* __restrict__ logLr, const float* __restrict__ Lim,
    const float* __restrict__ logDt, float2* __restrict__ part)
{
    __shared__ unsigned short us[32][136];   // u tile bf16 [l][h], pad 8 (8704 B)
    __shared__ unsigned xs[32 * 129];        // out tile [l][128 complex], pitch 129

    const int m  = blockIdx.x;               // 32-l chunk, 0..63
    const int ph = blockIdx.y;               // p-half, 0..1
    const int b  = blockIdx.z;
    const int tid = threadIdx.x;
    const int w = tid >> 6, lane = tid & 63;
    const int q = lane >> 4, c = lane & 15;
    const int pbase = ph * 256 + w * 64;     // wave's 64 p' (global)
    const int l0 = m * 32;

    {   // stage u tile (32 l x 128 h) fp32 -> bf16 LDS
        const int lrow = tid >> 3;
        const int hcol = (tid & 7) * 16;
        const float* up = u + (size_t)(l0 + lrow) * (NB * NH) + b * NH + hcol;
        float4 a = *(const float4*)(up + 0);
        float4 d = *(const float4*)(up + 4);
        float4 e = *(const float4*)(up + 8);
        float4 g = *(const float4*)(up + 12);
        uint4 w0, w1;
        w0.x = (unsigned)f2bf(a.x) | ((unsigned)f2bf(a.y) << 16);
        w0.y = (unsigned)f2bf(a.z) | ((unsigned)f2bf(a.w) << 16);
        w0.z = (unsigned)f2bf(d.x) | ((unsigned)f2bf(d.y) << 16);
        w0.w = (unsigned)f2bf(d.z) | ((unsigned)f2bf(d.w) << 16);
        w1.x = (unsigned)f2bf(e.x) | ((unsigned)f2bf(e.y) << 16);
        w1.y = (unsigned)f2bf(e.z) | ((unsigned)f2bf(e.w) << 16);
        w1.z = (unsigned)f2bf(g.x) | ((unsigned)f2bf(g.y) << 16);
        w1.w = (unsigned)f2bf(g.z) | ((unsigned)f2bf(g.w) << 16);
        *(uint4*)&us[lrow][hcol + 0] = w0;
        *(uint4*)&us[lrow][hcol + 8] = w1;
    }
    __syncthreads();   // us ready

    f32x4 acc[4][2];
    #pragma unroll
    for (int mt = 0; mt < 4; ++mt)
        #pragma unroll
        for (int nt = 0; nt < 2; ++nt) acc[mt][nt] = (f32x4){0.f, 0.f, 0.f, 0.f};

    #pragma unroll
    for (int kk = 0; kk < 4; ++kk) {
        bf16x8 af[4];
        #pragma unroll
        for (int mt = 0; mt < 4; ++mt)
            af[mt] = *(const bf16x8*)(BhatF + ((size_t)kk << 14)
                                      + ((pbase + 16 * mt + c) << 5) + 8 * q);
        bf16x8 bfr[2];
        #pragma unroll
        for (int nt = 0; nt < 2; ++nt)
            bfr[nt] = *(const bf16x8*)&us[16 * nt + c][kk * 32 + 8 * q];
        #pragma unroll
        for (int mt = 0; mt < 4; ++mt)
            #pragma unroll
            for (int nt = 0; nt < 2; ++nt)
                acc[mt][nt] = __builtin_amdgcn_mfma_f32_16x16x32_bf16(
                    af[mt], bfr[nt], acc[mt][nt], 0, 0, 0);
    }

    // stash xs (bf16 pack — identical rounding everywhere)
    #pragma unroll
    for (int mt = 0; mt < 4; ++mt)
        #pragma unroll
        for (int nt = 0; nt < 2; ++nt) {
            const int rw  = 16 * nt + c;              // local l row
            const int ppl = w * 64 + 16 * mt + 4 * q; // local p' (0..255)
            ushort4 st;
            st.x = f2bf(acc[mt][nt][0]); st.y = f2bf(acc[mt][nt][1]);
            st.z = f2bf(acc[mt][nt][2]); st.w = f2bf(acc[mt][nt][3]);
            const int col = (ppl >> 1);               // local complex index 0..127
            xs[rw * 129 + col]     = (unsigned)st.x | ((unsigned)st.y << 16);
            xs[rw * 129 + col + 1] = (unsigned)st.z | ((unsigned)st.w << 16);
        }
    __syncthreads();   // xs ready

    // carry-only scan over 32 rows; threads 0..127 own this half's complex cols
    if (tid < 128) {
        float wr, wi; discretize(logLr, Lim, logDt, ph * 128 + tid, wr, wi);
        float sr = 0.f, si = 0.f;
        unsigned va[8], vb[8];
        #pragma unroll
        for (int j = 0; j < 8; ++j) va[j] = xs[j * 129 + tid];
        #pragma unroll
        for (int k8 = 0; k8 < 4; ++k8) {
            if (k8 < 3) {
                #pragma unroll
                for (int j = 0; j < 8; ++j) vb[j] = xs[((k8 + 1) * 8 + j) * 129 + tid];
            }
            #pragma unroll
            for (int j = 0; j < 8; ++j) {
                const float xr = bf2f((unsigned short)(va[j] & 0xffffu));
                const float xi = bf2f((unsigned short)(va[j] >> 16));
                const float tr = wr * sr - wi * si + xr;
                const float ti = wr * si + wi * sr + xi;
                sr = tr; si = ti;
            }
            #pragma unroll
            for (int j = 0; j < 8; ++j) va[j] = vb[j];
        }
        part[((size_t)b * 64 + m) * NP + ph * 128 + tid] = make_float2(sr, si);
    }
}

// ---------------------------------------------------------------------------
// gF: fused ENTRY-SCAN + GEMM1-recompute + replay + GEMM2 per (b, 32-l chunk).
// NEW this round: s2 kernel deleted — each block computes its own entry by
// scanning the carry prefix part[b][0..m-1][p] (thread tid owns p=tid) with
// W32 = w^32 in the exact j-order s2 used -> bitwise-identical entries.
// part is 4 MB (L2-resident); prefix reads are coalesced 2 KB per step,
// 8-batched. LDS = us 8704 + osb 16384 + es 2048 = 27136 B -> 6 blocks/CU
// (same tier as r8's 25088).
// ---------------------------------------------------------------------------
__global__ __launch_bounds__(256, 4) void gF(
    const float* __restrict__ u, const unsigned short* __restrict__ BhatF,
    const unsigned short* __restrict__ ChatF,
    const float* __restrict__ logLr, const float* __restrict__ Lim,
    const float* __restrict__ logDt, const float2* __restrict__ carr,
    const float* __restrict__ Dv, float* __restrict__ out)
{
    __shared__ unsigned short us[32][136];   // u tile bf16 (8704 B)
    __shared__ char osb[16384];              // o half-tile [32 l][128 complex], swizzled
    __shared__ float2 es[NP];                // entry state per p (2048 B)

    const int m = blockIdx.x, b = blockIdx.y;   // m: 32-l chunk, 0..63
    const int tid = threadIdx.x;
    const int w = tid >> 6, lane = tid & 63;
    const int q = lane >> 4, c = lane & 15;
    const int hbase = w * 32;              // GEMM2: wave owns a 32-h quadrant
    const int l0 = m * 32;

    // ---- prologue: entry from carry prefix (replaces s2; bitwise = s2) ----
    {
        float wr, wi; discretize(logLr, Lim, logDt, tid, wr, wi);
        float Wr = wr, Wi = wi;
        #pragma unroll
        for (int t = 0; t < 5; ++t) { const float r = Wr * Wr - Wi * Wi;
                                      Wi = 2.f * Wr * Wi; Wr = r; }   // w^32
        float sr = 0.f, si = 0.f;
        const float2* cp = carr + (size_t)b * 64 * NP + tid;
        int j = 0;
        for (; j + 8 <= m; j += 8) {
            float2 vv[8];
            #pragma unroll
            for (int k = 0; k < 8; ++k) vv[k] = cp[(size_t)(j + k) * NP];
            #pragma unroll
            for (int k = 0; k < 8; ++k) {
                const float tr = Wr * sr - Wi * si + vv[k].x;
                const float ti = Wr * si + Wi * sr + vv[k].y;
                sr = tr; si = ti;
            }
        }
        for (; j < m; ++j) {
            const float2 v = cp[(size_t)j * NP];
            const float tr = Wr * sr - Wi * si + v.x;
            const float ti = Wr * si + Wi * sr + v.y;
            sr = tr; si = ti;
        }
        es[tid] = make_float2(sr, si);
    }

    {   // stage u tile (shared by both halves' GEMM1)
        const int lrow = tid >> 3;
        const int hcol = (tid & 7) * 16;
        const float* up = u + (size_t)(l0 + lrow) * (NB * NH) + b * NH + hcol;
        float4 a = *(const float4*)(up + 0);
        float4 d = *(const float4*)(up + 4);
        float4 e = *(const float4*)(up + 8);
        float4 g = *(const float4*)(up + 12);
        uint4 w0, w1;
        w0.x = (unsigned)f2bf(a.x) | ((unsigned)f2bf(a.y) << 16);
        w0.y = (unsigned)f2bf(a.z) | ((unsigned)f2bf(a.w) << 16);
        w0.z = (unsigned)f2bf(d.x) | ((unsigned)f2bf(d.y) << 16);
        w0.w = (unsigned)f2bf(d.z) | ((unsigned)f2bf(d.w) << 16);
        w1.x = (unsigned)f2bf(e.x) | ((unsigned)f2bf(e.y) << 16);
        w1.y = (unsigned)f2bf(e.z) | ((unsigned)f2bf(e.w) << 16);
        w1.z = (unsigned)f2bf(g.x) | ((unsigned)f2bf(g.y) << 16);
        w1.w = (unsigned)f2bf(g.z) | ((unsigned)f2bf(g.w) << 16);
        *(uint4*)&us[lrow][hcol + 0] = w0;
        *(uint4*)&us[lrow][hcol + 8] = w1;
    }
    __syncthreads();   // us + es ready

    f32x4 acc2[2][2];
    #pragma unroll
    for (int mt = 0; mt < 2; ++mt)
        #pragma unroll
        for (int nt = 0; nt < 2; ++nt) acc2[mt][nt] = (f32x4){0.f, 0.f, 0.f, 0.f};

    #pragma unroll 1
    for (int half = 0; half < 2; ++half) {
        // ---- GEMM1 recompute for this half (identical fragments to gA) ----
        const int pbase = half * 256 + w * 64;
        f32x4 acc[4][2];
        #pragma unroll
        for (int mt = 0; mt < 4; ++mt)
            #pragma unroll
            for (int nt = 0; nt < 2; ++nt) acc[mt][nt] = (f32x4){0.f, 0.f, 0.f, 0.f};
        #pragma unroll
        for (int kk = 0; kk < 4; ++kk) {
            bf16x8 af[4];
            #pragma unroll
            for (int mt = 0; mt < 4; ++mt)
                af[mt] = *(const bf16x8*)(BhatF + ((size_t)kk << 14)
                                          + ((pbase + 16 * mt + c) << 5) + 8 * q);
            bf16x8 bfr[2];
            #pragma unroll
            for (int nt = 0; nt < 2; ++nt)
                bfr[nt] = *(const bf16x8*)&us[16 * nt + c][kk * 32 + 8 * q];
            #pragma unroll
            for (int mt = 0; mt < 4; ++mt)
                #pragma unroll
                for (int nt = 0; nt < 2; ++nt)
                    acc[mt][nt] = __builtin_amdgcn_mfma_f32_16x16x32_bf16(
                        af[mt], bfr[nt], acc[mt][nt], 0, 0, 0);
        }

        // ---- stash bf16 Bu into swizzled osb ----
        #pragma unroll
        for (int mt = 0; mt < 4; ++mt)
            #pragma unroll
            for (int nt = 0; nt < 2; ++nt) {
                const int row  = 16 * nt + c;
                const int col2 = w * 32 + 8 * mt + 2 * q;   // complex col, even
                ushort4 st;
                st.x = f2bf(acc[mt][nt][0]); st.y = f2bf(acc[mt][nt][1]);
                st.z = f2bf(acc[mt][nt][2]); st.w = f2bf(acc[mt][nt][3]);
                const unsigned byte = (((unsigned)row << 9)
                                       + (((unsigned)col2 << 2)
                                          ^ (((unsigned)(row & 7)) << 4)));
                uint2 st2 = { (unsigned)st.x | ((unsigned)st.y << 16),
                              (unsigned)st.z | ((unsigned)st.w << 16) };
                *(uint2*)(osb + byte) = st2;
            }
        __syncthreads();   // osb Bu ready

        // ---- replay in place from entry (threads 0..127, batch-loaded) ----
        if (tid < 128) {
            const int p = half * 128 + tid;
            float wr, wi; discretize(logLr, Lim, logDt, p, wr, wi);
            const float2 E = es[p];
            float sr = E.x, si = E.y;
            unsigned va[32];
            #pragma unroll
            for (int j = 0; j < 32; ++j) {
                const unsigned byte = (((unsigned)j << 9)
                                       + (((unsigned)tid << 2)
                                          ^ (((unsigned)(j & 7)) << 4)));
                va[j] = *(const unsigned*)(osb + byte);
            }
            #pragma unroll
            for (int j = 0; j < 32; ++j) {
                const float xr = bf2f((unsigned short)(va[j] & 0xffffu));
                const float xi = bf2f((unsigned short)(va[j] >> 16));
                const float tr = wr * sr - wi * si + xr;
                const float ti = wr * si + wi * sr + xi;
                sr = tr; si = ti;
                va[j] = (unsigned)f2bf(tr) | ((unsigned)f2bf(ti) << 16);
            }
            #pragma unroll
            for (int j = 0; j < 32; ++j) {
                const unsigned byte = (((unsigned)j << 9)
                                       + (((unsigned)tid << 2)
                                          ^ (((unsigned)(j & 7)) << 4)));
                *(unsigned*)(osb + byte) = va[j];
            }
        }
        __syncthreads();   // replayed o ready

        // ---- GEMM2 this half's 8 kk (acc2 persists across halves) ----
        #pragma unroll 4
        for (int kl = 0; kl < 8; ++kl) {
            const int kk = half * 8 + kl;
            bf16x8 af2[2];
            #pragma unroll
            for (int mt = 0; mt < 2; ++mt)
                af2[mt] = *(const bf16x8*)(ChatF + ((size_t)kk << 12)
                                           + ((hbase + (mt << 4) + c) << 5) + (q << 3));
            bf16x8 bfr2[2];
            #pragma unroll
            for (int nt = 0; nt < 2; ++nt) {
                const int r = 16 * nt + c;
                const unsigned byte = ((((unsigned)r << 9) + ((unsigned)kl << 6)
                                        + ((unsigned)q << 4))
                                       ^ (((unsigned)(c & 7)) << 4));
                bfr2[nt] = *(const bf16x8*)(osb + byte);
            }
            #pragma unroll
            for (int mt = 0; mt < 2; ++mt)
                #pragma unroll
                for (int nt = 0; nt < 2; ++nt)
                    acc2[mt][nt] = __builtin_amdgcn_mfma_f32_16x16x32_bf16(
                        af2[mt], bfr2[nt], acc2[mt][nt], 0, 0, 0);
        }
        if (half == 0) __syncthreads();     // osb consumed before overwrite
    }

    // ---- epilogue: D-term + out ----
    #pragma unroll
    for (int mt = 0; mt < 2; ++mt) {
        const int h4 = hbase + 16 * mt + 4 * q;
        const float4 dd = *(const float4*)(Dv + h4);
        #pragma unroll
        for (int nt = 0; nt < 2; ++nt) {
            const int l = l0 + 16 * nt + c;
            const size_t off = ((size_t)l * NB + b) * NH + h4;
            const float4 uu = *(const float4*)(u + off);
            float4 ov;
            ov.x = acc2[mt][nt][0] + dd.x * uu.x;
            ov.y = acc2[mt][nt][1] + dd.y * uu.y;
            ov.z = acc2[mt][nt][2] + dd.z * uu.z;
            ov.w = acc2[mt][nt][3] + dd.w * uu.w;
            *(float4*)(out + off) = ov;
        }
    }
}

extern "C" void kernel_launch(void* const* d_in, const int* in_sizes, int n_in,
                              void* d_out, int out_size, void* d_ws, size_t ws_size,
                              hipStream_t stream)
{
    const float* u     = (const float*)d_in[0];
    const float* logLr = (const float*)d_in[1];
    const float* Lim   = (const float*)d_in[2];
    const float* Btr   = (const float*)d_in[3];
    const float* Bti   = (const float*)d_in[4];
    const float* Ctr   = (const float*)d_in[5];
    const float* Cti   = (const float*)d_in[6];
    const float* Dv    = (const float*)d_in[7];
    const float* logDt = (const float*)d_in[8];
    float* out = (float*)d_out;

    char* ws = (char*)d_ws;
    float2*         part = (float2*)ws;                          //  4,194,304 B (raw carries, read-only in gF)
    unsigned short* Bhat = (unsigned short*)(ws + 4194304);      //    131,072 B (BhatF)
    unsigned short* Chat = (unsigned short*)(ws + 4325376);      //    131,072 B (ChatF)

    k0<<<dim3((NP * NH) / 256), 256, 0, stream>>>(logLr, Lim, logDt,
                                                  Btr, Bti, Ctr, Cti, Bhat, Chat);
    gA<<<dim3(SL / 32, 2, NB), 256, 0, stream>>>(u, Bhat, logLr, Lim, logDt, part);
    gF<<<dim3(SL / 32, NB), 256, 0, stream>>>(u, Bhat, Chat, logLr, Lim, logDt,
                                              part, Dv, out);
}